// Round 10
// baseline (1263.346 us; speedup 1.0000x reference)
//
#include <hip/hip_runtime.h>

// B=16, G=128, F=1024, H=512, N=B*G=2048, rows M = B*N = 32768.
#define NN 2048
#define FD 1024
#define HD 512
#define MR 32768

typedef __attribute__((ext_vector_type(8))) short bf16x8;   // 8 bf16 = 4 VGPR
typedef __attribute__((ext_vector_type(4))) float f32x4;    // mfma 16x16 accumulator

static constexpr float BNS = 0.99999500003749962f;  // 1/sqrt(1+1e-5)

__device__ __forceinline__ float lrelu(float x) { return x > 0.f ? x : 0.1f * x; }

// fp32 -> bf16 round-to-nearest-even (normal floats only; no NaN path needed)
__device__ __forceinline__ unsigned short f2bf(float x) {
  unsigned u = __float_as_uint(x);
  u += 0x7fffu + ((u >> 16) & 1u);
  return (unsigned short)(u >> 16);
}
__device__ __forceinline__ float bf2f(unsigned short h) {
  return __uint_as_float(((unsigned)h) << 16);
}

// ---- split fp32 plane into bf16 hi + bf16 lo (residual), row-major ----
__global__ __launch_bounds__(256) void split_rm(const float* __restrict__ src,
                                                unsigned short* __restrict__ hi,
                                                unsigned short* __restrict__ lo, int n4) {
  for (int i = blockIdx.x * 256 + threadIdx.x; i < n4; i += gridDim.x * 256) {
    float4 v = ((const float4*)src)[i];
    ushort4 h, l;
    h.x = f2bf(v.x); l.x = f2bf(v.x - bf2f(h.x));
    h.y = f2bf(v.y); l.y = f2bf(v.y - bf2f(h.y));
    h.z = f2bf(v.z); l.z = f2bf(v.z - bf2f(h.z));
    h.w = f2bf(v.w); l.w = f2bf(v.w - bf2f(h.w));
    ((ushort4*)hi)[i] = h;
    ((ushort4*)lo)[i] = l;
  }
}

// ---- split (w + I): adds 1.0 on the diagonal, then hi/lo split ----
__global__ __launch_bounds__(256) void split_w(const float* __restrict__ src,
                                               unsigned short* __restrict__ hi,
                                               unsigned short* __restrict__ lo) {
  for (int i = blockIdx.x * 256 + threadIdx.x; i < NN * NN / 4; i += gridDim.x * 256) {
    float4 v = ((const float4*)src)[i];
    const int e0 = i * 4;
    const int row = e0 >> 11;           // NN = 2048
    const int dcol = row - (e0 & (NN - 1));
    if (dcol == 0) v.x += 1.0f;
    else if (dcol == 1) v.y += 1.0f;
    else if (dcol == 2) v.z += 1.0f;
    else if (dcol == 3) v.w += 1.0f;
    ushort4 h, l;
    h.x = f2bf(v.x); l.x = f2bf(v.x - bf2f(h.x));
    h.y = f2bf(v.y); l.y = f2bf(v.y - bf2f(h.y));
    h.z = f2bf(v.z); l.z = f2bf(v.z - bf2f(h.z));
    h.w = f2bf(v.w); l.w = f2bf(v.w - bf2f(h.w));
    ((ushort4*)hi)[i] = h;
    ((ushort4*)lo)[i] = l;
  }
}

// ---- split + transpose: src[K][N] fp32 -> hi/lo[N][K] bf16 (weights -> K-major) ----
__global__ __launch_bounds__(256) void split_tr(const float* __restrict__ src,
                                                unsigned short* __restrict__ hi,
                                                unsigned short* __restrict__ lo,
                                                int K, int N) {
  __shared__ float t[32][33];
  const int n0 = blockIdx.x * 32, k0 = blockIdx.y * 32;
  const int tx = threadIdx.x & 31, ty = threadIdx.x >> 5;
  for (int i = ty; i < 32; i += 8) t[i][tx] = src[(size_t)(k0 + i) * N + n0 + tx];
  __syncthreads();
  for (int i = ty; i < 32; i += 8) {
    float v = t[tx][i];  // = src[k0+tx][n0+i]
    unsigned short h = f2bf(v);
    size_t o = (size_t)(n0 + i) * K + k0 + tx;
    hi[o] = h;
    lo[o] = f2bf(v - bf2f(h));
  }
}

// dinv[n] = (1 + sum_j w[n,j])^{-1/2}   (+1 covers the identity diagonal)
__global__ __launch_bounds__(256) void dinv_kernel(const float* __restrict__ w,
                                                   float* __restrict__ dinv) {
  const int n = blockIdx.x;
  const float* row = w + (size_t)n * NN;
  float s = 0.f;
  for (int i = threadIdx.x; i < NN; i += 256) s += row[i];
#pragma unroll
  for (int off = 32; off > 0; off >>= 1) s += __shfl_down(s, off);
  __shared__ float red[4];
  const int lane = threadIdx.x & 63, wid = threadIdx.x >> 6;
  if (lane == 0) red[wid] = s;
  __syncthreads();
  if (threadIdx.x == 0) dinv[n] = 1.0f / sqrtf(red[0] + red[1] + red[2] + red[3] + 1.0f);
}

// ================= bf16x3 MFMA GEMM =================
// C[m][n] = sum_k (Ah+Al)[m][k] * (Bh+Bl)[k][n], via AhBh + AhBl + AlBh (fp32 acc).
// A row-major [M][K] bf16 planes; B K-major: Bt[N][K] bf16 planes.
// 256 threads = 4 waves (2x2), tile 128x128, BK=32, mfma_f32_16x16x32_bf16.
// LDS linear; staging swizzle: physical 16B-chunk (row r, cp) holds logical chunk
// cp ^ ((r>>1)&3), realized on the GLOBAL source address (m173 pattern); the
// fragment ds_read applies the same XOR (bits 1-2 of the LDS row == bits 1-2 of
// lq for both A and B), so lane (lq,lg) gets logical k-chunk lg. Note the
// slot->k bijection need not match HW's: it's identical for A and B, so the
// contraction is invariant to it.
// EPI 0: bn+lrelu -> hi/lo row-major                                        (X1)
// EPI 1: dinv[n]*bn+lrelu -> hi/lo TRANSPOSED per batch [b][f][node]       (t'^T)
// EPI 2: dinv[m]*acc -> hi/lo row-major, batched z   (graph prop; A already w+I)
// EPI 3: bn+lrelu -> fp32 row-major                                          (Y)
template <int EPI>
__global__ __launch_bounds__(256) void mfma_gemm(
    const unsigned short* __restrict__ Ah, const unsigned short* __restrict__ Al,
    const unsigned short* __restrict__ Bh, const unsigned short* __restrict__ Bl,
    const float* __restrict__ bias, const float* __restrict__ gam,
    const float* __restrict__ bet, const float* __restrict__ dinv,
    unsigned short* __restrict__ Ch, unsigned short* __restrict__ Cl,
    float* __restrict__ Cf, int M, int N, int K) {
  __shared__ unsigned short smem[4 * 4096];  // Ah|Al|Bh|Bl tiles, 8KB each = 32KB
  const char* smemc = (const char*)smem;
  const int tid = threadIdx.x;
  const int ln = tid & 63, wv = tid >> 6;
  const int wm = wv >> 1, wn = wv & 1;
  const int rowB = blockIdx.y * 128;
  const int colB = blockIdx.x * 128;
  const int z = (EPI == 2) ? blockIdx.z : 0;
  const size_t zB = (size_t)z * (size_t)N * (size_t)K;

  // Staging geometry: 512 16B-chunks per 128x32 tile; chunk q -> (r=q>>2, cp=q&3).
  int srow[2], scol[2];
#pragma unroll
  for (int i = 0; i < 2; i++) {
    int q = (i * 4 + wv) * 64 + ln;
    int r = q >> 2, cp = q & 3;
    srow[i] = r;
    scol[i] = (cp ^ ((r >> 1) & 3)) * 8;  // element offset within 32-elem row
  }
  const unsigned short* gAh = Ah + (size_t)rowB * K;
  const unsigned short* gAl = Al + (size_t)rowB * K;
  const unsigned short* gBh = Bh + zB + (size_t)colB * K;
  const unsigned short* gBl = Bl + zB + (size_t)colB * K;

  // Fragment ds_read offsets (bytes). Lane ln = 16*lg + lq.
  const int lq = ln & 15, lg = ln >> 4;
  const int swz = (lg ^ ((lq >> 1) & 3)) * 16;
  const int aoff = lq * 64 + swz + wm * 4096;
  const int boff = lq * 64 + swz + wn * 4096;

  f32x4 acc[4][4] = {};

#define STAGE(gp, toff)                                                              \
  _Pragma("unroll") for (int i = 0; i < 2; i++) {                                    \
    __builtin_amdgcn_global_load_lds(                                                \
        (const __attribute__((address_space(1))) unsigned int*)((gp) +               \
            (size_t)srow[i] * K + scol[i] + k0),                                     \
        (__attribute__((address_space(3))) unsigned int*)((char*)smem + (toff) +     \
            (i * 4 + wv) * 1024),                                                    \
        16, 0, 0);                                                                   \
  }

  for (int k0 = 0; k0 < K; k0 += 32) {
    __syncthreads();  // prior tile's ds_reads done -> safe to overwrite
    STAGE(gAh, 0)
    STAGE(gAl, 8192)
    STAGE(gBh, 16384)
    STAGE(gBl, 24576)
    __syncthreads();  // compiler drains vmcnt before s_barrier -> tile visible

    bf16x8 fah[4], fal[4], fbh[4], fbl[4];
#pragma unroll
    for (int m = 0; m < 4; m++) {
      fah[m] = *(const bf16x8*)(smemc + 0 + aoff + m * 1024);
      fal[m] = *(const bf16x8*)(smemc + 8192 + aoff + m * 1024);
    }
#pragma unroll
    for (int n = 0; n < 4; n++) {
      fbh[n] = *(const bf16x8*)(smemc + 16384 + boff + n * 1024);
      fbl[n] = *(const bf16x8*)(smemc + 24576 + boff + n * 1024);
    }
#pragma unroll
    for (int m = 0; m < 4; m++)
#pragma unroll
      for (int n = 0; n < 4; n++) {
        acc[m][n] = __builtin_amdgcn_mfma_f32_16x16x32_bf16(fah[m], fbh[n], acc[m][n], 0, 0, 0);
        acc[m][n] = __builtin_amdgcn_mfma_f32_16x16x32_bf16(fah[m], fbl[n], acc[m][n], 0, 0, 0);
        acc[m][n] = __builtin_amdgcn_mfma_f32_16x16x32_bf16(fal[m], fbh[n], acc[m][n], 0, 0, 0);
      }
  }
#undef STAGE

  const int baseRow = rowB + wm * 64;
  const int baseCol = colB + wn * 64;

  if (EPI == 1) {
    // Transposed epilogue via LDS (main-loop LDS is dead after the loop).
    // One n-quarter (16 output cols) at a time. Per-wave per-plane region:
    // [16 cols][68 rows] ushorts = 2176B; 4 waves = 8704B/plane; both planes
    // fit in 17408B < 32KB.
    unsigned short* ldsh = smem + wv * 1088;         // 16*68 ushorts
    unsigned short* ldsl = smem + 4352 + wv * 1088;  // +8704B
    const int b = baseRow >> 11;         // batch index (tile never crosses batch)
    const int nodeB = baseRow & (NN - 1);
#pragma unroll
    for (int n = 0; n < 4; n++) {
      __syncthreads();  // previous quarter's reads (or main-loop frag reads) done
      const int gcol = baseCol + n * 16 + lq;
      const float bi = bias[gcol], ga = gam[gcol], be = bet[gcol];
#pragma unroll
      for (int m = 0; m < 4; m++)
#pragma unroll
        for (int r = 0; r < 4; r++) {
          const int row = m * 16 + lg * 4 + r;  // node-local 0..63
          float v = acc[m][n][r] + bi;
          v = ga * (v * BNS) + be;
          v = lrelu(v) * dinv[(baseRow + row) & (NN - 1)];
          unsigned short h = f2bf(v);
          ldsh[lq * 68 + row] = h;
          ldsl[lq * 68 + row] = f2bf(v - bf2f(h));
        }
      __syncthreads();
      // 16 cols x 16 row-chunks(4) = 256 ushort4-stores / 64 lanes = 4 per lane.
#pragma unroll
      for (int it = 0; it < 4; it++) {
        const int c = it * 4 + lg;   // 0..15
        const int rr = lq * 4;       // 0..60
        ushort4 hv = *(const ushort4*)&ldsh[c * 68 + rr];
        ushort4 lv = *(const ushort4*)&ldsl[c * 68 + rr];
        const size_t o = (size_t)b * ((size_t)N * NN) +
                         (size_t)(baseCol + n * 16 + c) * NN + (nodeB + rr);
        *(ushort4*)&Ch[o] = hv;
        *(ushort4*)&Cl[o] = lv;
      }
    }
    return;
  }

#pragma unroll
  for (int m = 0; m < 4; m++) {
#pragma unroll
    for (int n = 0; n < 4; n++) {
#pragma unroll
      for (int r = 0; r < 4; r++) {
        const int row = baseRow + m * 16 + lg * 4 + r;  // C/D: row=(lane>>4)*4+reg
        const int col = baseCol + n * 16 + lq;          //      col=lane&15
        float v = acc[m][n][r];
        if (EPI == 0 || EPI == 3) {
          v += bias[col];
          v = gam[col] * (v * BNS) + bet[col];
          v = lrelu(v);
        }
        if (EPI == 0) {
          unsigned short h = f2bf(v);
          size_t o = (size_t)row * N + col;
          Ch[o] = h;
          Cl[o] = f2bf(v - bf2f(h));
        } else if (EPI == 2) {
          // A plane already holds w+I, so acc == ((w+I) @ t')[row][col].
          v = dinv[row] * v;
          unsigned short h = f2bf(v);
          size_t o = ((size_t)z * NN + row) * (size_t)N + col;
          Ch[o] = h;
          Cl[o] = f2bf(v - bf2f(h));
        } else if (EPI == 3) {
          Cf[(size_t)row * N + col] = v;
        }
      }
    }
  }
}

// result[r] = dot(Y[r,:], cls_W) + cls_b ; one wave per row
__global__ __launch_bounds__(256) void cls_kernel(const float* __restrict__ Y,
                                                  const float* __restrict__ clsW,
                                                  const float* __restrict__ clsb,
                                                  float* __restrict__ out) {
  const int gid = blockIdx.x * 256 + threadIdx.x;
  const int wave = gid >> 6, lane = gid & 63;
  const float* y = Y + (size_t)wave * HD;
  float s = 0.f;
#pragma unroll
  for (int i = 0; i < HD / 64; i++) s += y[lane + i * 64] * clsW[lane + i * 64];
#pragma unroll
  for (int off = 32; off > 0; off >>= 1) s += __shfl_down(s, off);
  if (lane == 0) out[wave] = s + clsb[0];
}

// Second tuple output: label int32 -> float32 (harness stores non-bf16 outputs as fp32)
__global__ __launch_bounds__(256) void label_kernel(const int* __restrict__ lab,
                                                    float* __restrict__ out) {
  const int i = blockIdx.x * 256 + threadIdx.x;
  out[i] = (float)lab[i];
}

extern "C" void kernel_launch(void* const* d_in, const int* in_sizes, int n_in,
                              void* d_out, int out_size, void* d_ws, size_t ws_size,
                              hipStream_t stream) {
  const float* d      = (const float*)d_in[0];
  const float* w      = (const float*)d_in[1];
  const int*   label  = (const int*)d_in[2];
  const float* rf_W1  = (const float*)d_in[3];
  const float* rf_b1  = (const float*)d_in[4];
  const float* rf_g1  = (const float*)d_in[5];
  const float* rf_be1 = (const float*)d_in[6];
  const float* rf_W2  = (const float*)d_in[7];
  const float* rf_b2  = (const float*)d_in[8];
  const float* rf_g2  = (const float*)d_in[9];
  const float* rf_be2 = (const float*)d_in[10];
  const float* fc_W   = (const float*)d_in[11];
  const float* fc_b   = (const float*)d_in[12];
  const float* fc_g   = (const float*)d_in[13];
  const float* fc_be  = (const float*)d_in[14];
  const float* cls_W  = (const float*)d_in[15];
  const float* cls_b  = (const float*)d_in[16];

  float* out = (float*)d_out;
  char* ws = (char*)d_ws;
  const size_t MB = 1024ull * 1024ull;
  // Workspace (peak ~282MB+8KB):
  //  R0 [0,128): d hi/lo -> t'^T hi/lo -> Y fp32 (first 64MB)
  //  R1 [128,256): X1 hi/lo -> dp hi/lo
  //  [256,272): (w+I) hi/lo ; [272,282): W1t/W2t/fcWt hi/lo ; [282]: dinv
  unsigned short* R0h = (unsigned short*)(ws);
  unsigned short* R0l = (unsigned short*)(ws + 64 * MB);
  unsigned short* R1h = (unsigned short*)(ws + 128 * MB);
  unsigned short* R1l = (unsigned short*)(ws + 192 * MB);
  unsigned short* wh  = (unsigned short*)(ws + 256 * MB);
  unsigned short* wl  = (unsigned short*)(ws + 264 * MB);
  unsigned short* W1th = (unsigned short*)(ws + 272 * MB);
  unsigned short* W1tl = (unsigned short*)(ws + 274 * MB);
  unsigned short* W2th = (unsigned short*)(ws + 276 * MB);
  unsigned short* W2tl = (unsigned short*)(ws + 278 * MB);
  unsigned short* fcth = (unsigned short*)(ws + 280 * MB);
  unsigned short* fctl = (unsigned short*)(ws + 281 * MB);
  float* dinvp = (float*)(ws + 282 * MB);
  float* Yf = (float*)(ws);  // reuse R0 after t'^T-hi is dead

  // Precompute: splits, transposed-split weights, dinv
  split_rm<<<2048, 256, 0, stream>>>(d, R0h, R0l, MR * FD / 4);
  split_w<<<1024, 256, 0, stream>>>(w, wh, wl);
  split_tr<<<dim3(FD / 32, FD / 32), 256, 0, stream>>>(rf_W1, W1th, W1tl, FD, FD);
  split_tr<<<dim3(FD / 32, FD / 32), 256, 0, stream>>>(rf_W2, W2th, W2tl, FD, FD);
  split_tr<<<dim3(HD / 32, FD / 32), 256, 0, stream>>>(fc_W, fcth, fctl, FD, HD);
  dinv_kernel<<<NN, 256, 0, stream>>>(w, dinvp);

  // Stage1: X1 = lrelu(bn(d @ W1))             [32768x1024]*[1024x1024] -> R1
  mfma_gemm<0><<<dim3(FD / 128, MR / 128), 256, 0, stream>>>(
      R0h, R0l, W1th, W1tl, rf_b1, rf_g1, rf_be1, nullptr, R1h, R1l, nullptr, MR, FD, FD);
  // Stage2: t' = dinv[n]*lrelu(bn(X1 @ W2)), written TRANSPOSED per batch -> R0
  mfma_gemm<1><<<dim3(FD / 128, MR / 128), 256, 0, stream>>>(
      R1h, R1l, W2th, W2tl, rf_b2, rf_g2, rf_be2, dinvp, R0h, R0l, nullptr, MR, FD, FD);
  // Stage3: dp[b] = dinv[m]*((w+I) @ t'[b])      batched z=16 -> R1
  mfma_gemm<2><<<dim3(FD / 128, NN / 128, 16), 256, 0, stream>>>(
      wh, wl, R0h, R0l, nullptr, nullptr, nullptr, dinvp, R1h, R1l, nullptr, NN, FD, NN);
  // Stage4: Y = lrelu(bn(dp @ fc_W)) fp32       [32768x1024]*[1024x512] -> R0
  mfma_gemm<3><<<dim3(HD / 128, MR / 128), 256, 0, stream>>>(
      R1h, R1l, fcth, fctl, fc_b, fc_g, fc_be, nullptr, nullptr, nullptr, Yf, MR, HD, FD);
  // CLS
  cls_kernel<<<MR / 4, 256, 0, stream>>>(Yf, cls_W, cls_b, out);
  // Label tuple output as fp32
  label_kernel<<<MR / 256, 256, 0, stream>>>(label, out + MR);
}

// Round 11
// 1094.493 us; speedup vs baseline: 1.1543x; 1.1543x over previous
//
#include <hip/hip_runtime.h>

// B=16, G=128, F=1024, H=512, N=B*G=2048, rows M = B*N = 32768.
#define NN 2048
#define FD 1024
#define HD 512
#define MR 32768

typedef __attribute__((ext_vector_type(8))) short bf16x8;   // 8 bf16 = 4 VGPR
typedef __attribute__((ext_vector_type(4))) float f32x4;    // mfma 16x16 accumulator

static constexpr float BNS = 0.99999500003749962f;  // 1/sqrt(1+1e-5)

__device__ __forceinline__ float lrelu(float x) { return x > 0.f ? x : 0.1f * x; }

// fp32 -> bf16 round-to-nearest-even (normal floats only; no NaN path needed)
__device__ __forceinline__ unsigned short f2bf(float x) {
  unsigned u = __float_as_uint(x);
  u += 0x7fffu + ((u >> 16) & 1u);
  return (unsigned short)(u >> 16);
}
__device__ __forceinline__ float bf2f(unsigned short h) {
  return __uint_as_float(((unsigned)h) << 16);
}

// ---- split fp32 plane into bf16 hi + bf16 lo (residual), row-major ----
__global__ __launch_bounds__(256) void split_rm(const float* __restrict__ src,
                                                unsigned short* __restrict__ hi,
                                                unsigned short* __restrict__ lo, int n4) {
  for (int i = blockIdx.x * 256 + threadIdx.x; i < n4; i += gridDim.x * 256) {
    float4 v = ((const float4*)src)[i];
    ushort4 h, l;
    h.x = f2bf(v.x); l.x = f2bf(v.x - bf2f(h.x));
    h.y = f2bf(v.y); l.y = f2bf(v.y - bf2f(h.y));
    h.z = f2bf(v.z); l.z = f2bf(v.z - bf2f(h.z));
    h.w = f2bf(v.w); l.w = f2bf(v.w - bf2f(h.w));
    ((ushort4*)hi)[i] = h;
    ((ushort4*)lo)[i] = l;
  }
}

// ---- split (w + I): adds 1.0 on the diagonal, then hi/lo split ----
__global__ __launch_bounds__(256) void split_w(const float* __restrict__ src,
                                               unsigned short* __restrict__ hi,
                                               unsigned short* __restrict__ lo) {
  for (int i = blockIdx.x * 256 + threadIdx.x; i < NN * NN / 4; i += gridDim.x * 256) {
    float4 v = ((const float4*)src)[i];
    const int e0 = i * 4;
    const int row = e0 >> 11;           // NN = 2048
    const int dcol = row - (e0 & (NN - 1));
    if (dcol == 0) v.x += 1.0f;
    else if (dcol == 1) v.y += 1.0f;
    else if (dcol == 2) v.z += 1.0f;
    else if (dcol == 3) v.w += 1.0f;
    ushort4 h, l;
    h.x = f2bf(v.x); l.x = f2bf(v.x - bf2f(h.x));
    h.y = f2bf(v.y); l.y = f2bf(v.y - bf2f(h.y));
    h.z = f2bf(v.z); l.z = f2bf(v.z - bf2f(h.z));
    h.w = f2bf(v.w); l.w = f2bf(v.w - bf2f(h.w));
    ((ushort4*)hi)[i] = h;
    ((ushort4*)lo)[i] = l;
  }
}

// ---- split + transpose: src[K][N] fp32 -> hi/lo[N][K] bf16 (weights -> K-major) ----
__global__ __launch_bounds__(256) void split_tr(const float* __restrict__ src,
                                                unsigned short* __restrict__ hi,
                                                unsigned short* __restrict__ lo,
                                                int K, int N) {
  __shared__ float t[32][33];
  const int n0 = blockIdx.x * 32, k0 = blockIdx.y * 32;
  const int tx = threadIdx.x & 31, ty = threadIdx.x >> 5;
  for (int i = ty; i < 32; i += 8) t[i][tx] = src[(size_t)(k0 + i) * N + n0 + tx];
  __syncthreads();
  for (int i = ty; i < 32; i += 8) {
    float v = t[tx][i];  // = src[k0+tx][n0+i]
    unsigned short h = f2bf(v);
    size_t o = (size_t)(n0 + i) * K + k0 + tx;
    hi[o] = h;
    lo[o] = f2bf(v - bf2f(h));
  }
}

// dinv[n] = (1 + sum_j w[n,j])^{-1/2}   (+1 covers the identity diagonal)
__global__ __launch_bounds__(256) void dinv_kernel(const float* __restrict__ w,
                                                   float* __restrict__ dinv) {
  const int n = blockIdx.x;
  const float* row = w + (size_t)n * NN;
  float s = 0.f;
  for (int i = threadIdx.x; i < NN; i += 256) s += row[i];
#pragma unroll
  for (int off = 32; off > 0; off >>= 1) s += __shfl_down(s, off);
  __shared__ float red[4];
  const int lane = threadIdx.x & 63, wid = threadIdx.x >> 6;
  if (lane == 0) red[wid] = s;
  __syncthreads();
  if (threadIdx.x == 0) dinv[n] = 1.0f / sqrtf(red[0] + red[1] + red[2] + red[3] + 1.0f);
}

// out[0..MR)   = cls_b  (accumulation base for the fused cls atomics)
// out[MR..2MR) = float(label)
__global__ __launch_bounds__(256) void init_out(const int* __restrict__ lab,
                                                const float* __restrict__ clsb,
                                                float* __restrict__ out) {
  const int i = blockIdx.x * 256 + threadIdx.x;
  if (i < MR) out[i] = clsb[0];
  else out[i] = (float)lab[i - MR];
}

// ================= bf16x3 MFMA GEMM =================
// C[m][n] = sum_k (Ah+Al)[m][k] * (Bh+Bl)[k][n], via AhBh + AhBl + AlBh (fp32 acc).
// A row-major [M][K] bf16 planes; B K-major: Bt[N][K] bf16 planes.
// 256 threads = 4 waves (2x2), tile 128x128, BK=64, mfma_f32_16x16x32_bf16.
// LDS 64KB (4 planes x [128][64] bf16). Staging swizzle: physical 16B-chunk
// (row r, cp of 8) holds logical chunk cp ^ (r&7), realized on the GLOBAL source
// address (m173 pattern); fragment ds_read applies the same XOR (bits 0-2 of
// every fragment row == lq&7), so lane (lq,lg) gets logical k-chunk kk*4+lg.
// Bank cover per b128 read: 8 lanes per disjoint 4-bank group = uniform = free.
// EPI 0: bn+lrelu -> hi/lo row-major                                        (X1)
// EPI 1: dinv[n]*bn+lrelu -> hi/lo TRANSPOSED per batch [b][f][node]       (t'^T)
// EPI 2: dinv[m]*acc -> hi/lo row-major, batched z   (graph prop; A already w+I)
// EPI 3: bn+lrelu, fused cls: atomicAdd(out[row], sum_col v*clsW[col])      (Y)
template <int EPI>
__global__ __launch_bounds__(256) void mfma_gemm(
    const unsigned short* __restrict__ Ah, const unsigned short* __restrict__ Al,
    const unsigned short* __restrict__ Bh, const unsigned short* __restrict__ Bl,
    const float* __restrict__ bias, const float* __restrict__ gam,
    const float* __restrict__ bet, const float* __restrict__ dinv,
    unsigned short* __restrict__ Ch, unsigned short* __restrict__ Cl,
    const float* __restrict__ clsW, float* __restrict__ outF,
    int M, int N, int K) {
  __shared__ unsigned short smem[4 * 8192];  // Ah|Al|Bh|Bl tiles, 16KB each = 64KB
  const char* smemc = (const char*)smem;
  const int tid = threadIdx.x;
  const int ln = tid & 63, wv = tid >> 6;
  const int wm = wv >> 1, wn = wv & 1;
  const int rowB = blockIdx.y * 128;
  const int colB = blockIdx.x * 128;
  const int z = (EPI == 2) ? blockIdx.z : 0;
  const size_t zB = (size_t)z * (size_t)N * (size_t)K;

  // Staging geometry: 1024 16B-chunks per 128x64 plane-tile; q=(r=q>>3, cp=q&7).
  int srow[4], scol[4];
#pragma unroll
  for (int it = 0; it < 4; it++) {
    int q = it * 256 + tid;
    int r = q >> 3, cp = q & 7;
    srow[it] = r;
    scol[it] = (cp ^ (r & 7)) * 8;  // element offset within 64-elem row
  }
  const unsigned short* gAh = Ah + (size_t)rowB * K;
  const unsigned short* gAl = Al + (size_t)rowB * K;
  const unsigned short* gBh = Bh + zB + (size_t)colB * K;
  const unsigned short* gBl = Bl + zB + (size_t)colB * K;

  // Fragment ds_read bases (bytes). Lane ln = 16*lg + lq. Row stride 128B.
  const int lq = ln & 15, lg = ln >> 4;
  const int arow = (wm * 64 + lq) * 128;
  const int brow = (wn * 64 + lq) * 128;

  f32x4 acc[4][4] = {};

#define STAGE(gp, toff)                                                              \
  _Pragma("unroll") for (int it = 0; it < 4; it++) {                                 \
    __builtin_amdgcn_global_load_lds(                                                \
        (const __attribute__((address_space(1))) unsigned int*)((gp) +               \
            (size_t)srow[it] * K + scol[it] + k0),                                   \
        (__attribute__((address_space(3))) unsigned int*)((char*)smem + (toff) +     \
            it * 4096 + wv * 1024),                                                  \
        16, 0, 0);                                                                   \
  }

  for (int k0 = 0; k0 < K; k0 += 64) {
    __syncthreads();  // prior tile's ds_reads done -> safe to overwrite
    STAGE(gAh, 0)
    STAGE(gAl, 16384)
    STAGE(gBh, 32768)
    STAGE(gBl, 49152)
    __syncthreads();  // compiler drains vmcnt before s_barrier -> tile visible

#pragma unroll
    for (int kk = 0; kk < 2; kk++) {
      const int cs = ((kk * 4 + lg) ^ (lq & 7)) * 16;
      bf16x8 fah[4], fal[4], fbh[4], fbl[4];
#pragma unroll
      for (int m = 0; m < 4; m++) {
        fah[m] = *(const bf16x8*)(smemc + 0 + arow + m * 2048 + cs);
        fal[m] = *(const bf16x8*)(smemc + 16384 + arow + m * 2048 + cs);
      }
#pragma unroll
      for (int n = 0; n < 4; n++) {
        fbh[n] = *(const bf16x8*)(smemc + 32768 + brow + n * 2048 + cs);
        fbl[n] = *(const bf16x8*)(smemc + 49152 + brow + n * 2048 + cs);
      }
#pragma unroll
      for (int m = 0; m < 4; m++)
#pragma unroll
        for (int n = 0; n < 4; n++) {
          acc[m][n] = __builtin_amdgcn_mfma_f32_16x16x32_bf16(fah[m], fbh[n], acc[m][n], 0, 0, 0);
          acc[m][n] = __builtin_amdgcn_mfma_f32_16x16x32_bf16(fah[m], fbl[n], acc[m][n], 0, 0, 0);
          acc[m][n] = __builtin_amdgcn_mfma_f32_16x16x32_bf16(fal[m], fbh[n], acc[m][n], 0, 0, 0);
        }
    }
  }
#undef STAGE

  const int baseRow = rowB + wm * 64;
  const int baseCol = colB + wn * 64;

  if (EPI == 1) {
    // Transposed epilogue via LDS (main-loop LDS dead after the loop).
    // One n-quarter (16 cols) at a time; per-wave per-plane [16][68] ushorts.
    unsigned short* ldsh = smem + wv * 1088;         // 16*68 ushorts
    unsigned short* ldsl = smem + 4352 + wv * 1088;  // +8704B
    const int b = baseRow >> 11;         // batch index (tile never crosses batch)
    const int nodeB = baseRow & (NN - 1);
#pragma unroll
    for (int n = 0; n < 4; n++) {
      __syncthreads();  // previous quarter's reads (or main-loop frag reads) done
      const int gcol = baseCol + n * 16 + lq;
      const float bi = bias[gcol], ga = gam[gcol], be = bet[gcol];
#pragma unroll
      for (int m = 0; m < 4; m++)
#pragma unroll
        for (int r = 0; r < 4; r++) {
          const int row = m * 16 + lg * 4 + r;  // node-local 0..63
          float v = acc[m][n][r] + bi;
          v = ga * (v * BNS) + be;
          v = lrelu(v) * dinv[(baseRow + row) & (NN - 1)];
          unsigned short h = f2bf(v);
          ldsh[lq * 68 + row] = h;
          ldsl[lq * 68 + row] = f2bf(v - bf2f(h));
        }
      __syncthreads();
#pragma unroll
      for (int it = 0; it < 4; it++) {
        const int c = it * 4 + lg;   // 0..15
        const int rr = lq * 4;       // 0..60
        ushort4 hv = *(const ushort4*)&ldsh[c * 68 + rr];
        ushort4 lv = *(const ushort4*)&ldsl[c * 68 + rr];
        const size_t o = (size_t)b * ((size_t)N * NN) +
                         (size_t)(baseCol + n * 16 + c) * NN + (nodeB + rr);
        *(ushort4*)&Ch[o] = hv;
        *(ushort4*)&Cl[o] = lv;
      }
    }
    return;
  }

  if (EPI == 3) {
    // Fused FC epilogue + cls GEMV: partial = sum_col lrelu(bn(acc))*clsW[col],
    // shfl-reduce over the 16 lq lanes sharing each row, 1 atomicAdd per wave.
    float bi[4], ga[4], be[4], cw[4];
#pragma unroll
    for (int n = 0; n < 4; n++) {
      const int col = baseCol + n * 16 + lq;
      bi[n] = bias[col]; ga[n] = gam[col]; be[n] = bet[col]; cw[n] = clsW[col];
    }
#pragma unroll
    for (int m = 0; m < 4; m++)
#pragma unroll
      for (int r = 0; r < 4; r++) {
        const int row = baseRow + m * 16 + lg * 4 + r;
        float part = 0.f;
#pragma unroll
        for (int n = 0; n < 4; n++) {
          float v = acc[m][n][r] + bi[n];
          v = ga[n] * (v * BNS) + be[n];
          part += lrelu(v) * cw[n];
        }
        part += __shfl_xor(part, 1);
        part += __shfl_xor(part, 2);
        part += __shfl_xor(part, 4);
        part += __shfl_xor(part, 8);
        if (lq == 0) atomicAdd(&outF[row], part);
      }
    return;
  }

#pragma unroll
  for (int m = 0; m < 4; m++) {
#pragma unroll
    for (int n = 0; n < 4; n++) {
#pragma unroll
      for (int r = 0; r < 4; r++) {
        const int row = baseRow + m * 16 + lg * 4 + r;  // C/D: row=(lane>>4)*4+reg
        const int col = baseCol + n * 16 + lq;          //      col=lane&15
        float v = acc[m][n][r];
        if (EPI == 0) {
          v += bias[col];
          v = gam[col] * (v * BNS) + bet[col];
          v = lrelu(v);
          unsigned short h = f2bf(v);
          size_t o = (size_t)row * N + col;
          Ch[o] = h;
          Cl[o] = f2bf(v - bf2f(h));
        } else if (EPI == 2) {
          // A plane already holds w+I, so acc == ((w+I) @ t')[row][col].
          v = dinv[row] * v;
          unsigned short h = f2bf(v);
          size_t o = ((size_t)z * NN + row) * (size_t)N + col;
          Ch[o] = h;
          Cl[o] = f2bf(v - bf2f(h));
        }
      }
    }
  }
}

extern "C" void kernel_launch(void* const* d_in, const int* in_sizes, int n_in,
                              void* d_out, int out_size, void* d_ws, size_t ws_size,
                              hipStream_t stream) {
  const float* d      = (const float*)d_in[0];
  const float* w      = (const float*)d_in[1];
  const int*   label  = (const int*)d_in[2];
  const float* rf_W1  = (const float*)d_in[3];
  const float* rf_b1  = (const float*)d_in[4];
  const float* rf_g1  = (const float*)d_in[5];
  const float* rf_be1 = (const float*)d_in[6];
  const float* rf_W2  = (const float*)d_in[7];
  const float* rf_b2  = (const float*)d_in[8];
  const float* rf_g2  = (const float*)d_in[9];
  const float* rf_be2 = (const float*)d_in[10];
  const float* fc_W   = (const float*)d_in[11];
  const float* fc_b   = (const float*)d_in[12];
  const float* fc_g   = (const float*)d_in[13];
  const float* fc_be  = (const float*)d_in[14];
  const float* cls_W  = (const float*)d_in[15];
  const float* cls_b  = (const float*)d_in[16];

  float* out = (float*)d_out;
  char* ws = (char*)d_ws;
  const size_t MB = 1024ull * 1024ull;
  // Workspace (peak ~282MB+8KB):
  //  R0 [0,128): d hi/lo -> t'^T hi/lo
  //  R1 [128,256): X1 hi/lo -> dp hi/lo
  //  [256,272): (w+I) hi/lo ; [272,282): W1t/W2t/fcWt hi/lo ; [282]: dinv
  unsigned short* R0h = (unsigned short*)(ws);
  unsigned short* R0l = (unsigned short*)(ws + 64 * MB);
  unsigned short* R1h = (unsigned short*)(ws + 128 * MB);
  unsigned short* R1l = (unsigned short*)(ws + 192 * MB);
  unsigned short* wh  = (unsigned short*)(ws + 256 * MB);
  unsigned short* wl  = (unsigned short*)(ws + 264 * MB);
  unsigned short* W1th = (unsigned short*)(ws + 272 * MB);
  unsigned short* W1tl = (unsigned short*)(ws + 274 * MB);
  unsigned short* W2th = (unsigned short*)(ws + 276 * MB);
  unsigned short* W2tl = (unsigned short*)(ws + 278 * MB);
  unsigned short* fcth = (unsigned short*)(ws + 280 * MB);
  unsigned short* fctl = (unsigned short*)(ws + 281 * MB);
  float* dinvp = (float*)(ws + 282 * MB);

  // Precompute: splits, transposed-split weights, dinv, output init (cls_b/label)
  split_rm<<<2048, 256, 0, stream>>>(d, R0h, R0l, MR * FD / 4);
  split_w<<<1024, 256, 0, stream>>>(w, wh, wl);
  split_tr<<<dim3(FD / 32, FD / 32), 256, 0, stream>>>(rf_W1, W1th, W1tl, FD, FD);
  split_tr<<<dim3(FD / 32, FD / 32), 256, 0, stream>>>(rf_W2, W2th, W2tl, FD, FD);
  split_tr<<<dim3(HD / 32, FD / 32), 256, 0, stream>>>(fc_W, fcth, fctl, FD, HD);
  dinv_kernel<<<NN, 256, 0, stream>>>(w, dinvp);
  init_out<<<2 * MR / 256, 256, 0, stream>>>(label, cls_b, out);

  // Stage1: X1 = lrelu(bn(d @ W1))             [32768x1024]*[1024x1024] -> R1
  mfma_gemm<0><<<dim3(FD / 128, MR / 128), 256, 0, stream>>>(
      R0h, R0l, W1th, W1tl, rf_b1, rf_g1, rf_be1, nullptr, R1h, R1l, nullptr, nullptr,
      MR, FD, FD);
  // Stage2: t' = dinv[n]*lrelu(bn(X1 @ W2)), written TRANSPOSED per batch -> R0
  mfma_gemm<1><<<dim3(FD / 128, MR / 128), 256, 0, stream>>>(
      R1h, R1l, W2th, W2tl, rf_b2, rf_g2, rf_be2, dinvp, R0h, R0l, nullptr, nullptr,
      MR, FD, FD);
  // Stage3: dp[b] = dinv[m]*((w+I) @ t'[b])      batched z=16 -> R1
  mfma_gemm<2><<<dim3(FD / 128, NN / 128, 16), 256, 0, stream>>>(
      wh, wl, R0h, R0l, nullptr, nullptr, nullptr, dinvp, R1h, R1l, nullptr, nullptr,
      NN, FD, NN);
  // Stage4+CLS fused: out[row] += sum_col lrelu(bn(dp @ fc_W))[row][col]*cls_W[col]
  mfma_gemm<3><<<dim3(HD / 128, MR / 128), 256, 0, stream>>>(
      R1h, R1l, fcth, fctl, fc_b, fc_g, fc_be, nullptr, nullptr, nullptr, cls_W, out,
      MR, HD, FD);
}